// Round 4
// baseline (2091.672 us; speedup 1.0000x reference)
//
#include <hip/hip_runtime.h>
#include <hip/hip_bf16.h>
#include <math.h>

typedef __attribute__((ext_vector_type(8))) short short8;
typedef __attribute__((ext_vector_type(4))) float floatx4;
typedef __attribute__((ext_vector_type(4))) unsigned short ushort4v;

#define SCALE_F 0.17677669529663689f  // 1/sqrt(32)

__device__ __forceinline__ float bf2f(__hip_bfloat16 v){ return __bfloat162float(v); }

// ---------------- weight cast + transpose: src fp32 (K x N) -> dst bf16 (N x K) ----------------
__global__ void wcast_t(const float* __restrict__ src, __hip_bfloat16* __restrict__ dst, int K, int N)
{
    int idx = blockIdx.x * 256 + threadIdx.x;
    if (idx >= K * N) return;
    int n = idx / K, k = idx - n * K;
    dst[idx] = __float2bfloat16(src[(size_t)k * N + n]);
}

// ---------------- LayerNorm (token order) -> bf16 rows ----------------
__global__ __launch_bounds__(256)
void ln_kernel(const float* __restrict__ x, const float* __restrict__ g,
               const float* __restrict__ bb, __hip_bfloat16* __restrict__ out, int b0)
{
    int wave = threadIdx.x >> 6, lane = threadIdx.x & 63;
    int wr = blockIdx.x * 4 + wave;
    const float* xr = x + ((size_t)b0 * 3136 + wr) * 192;
    float v0 = xr[lane], v1 = xr[lane + 64], v2 = xr[lane + 128];
    float s = v0 + v1 + v2, ss = v0 * v0 + v1 * v1 + v2 * v2;
    #pragma unroll
    for (int o = 32; o; o >>= 1) { s += __shfl_xor(s, o); ss += __shfl_xor(ss, o); }
    float mu = s * (1.f / 192.f);
    float rs = rsqrtf(ss * (1.f / 192.f) - mu * mu + 1e-5f);
    __hip_bfloat16* op = out + (size_t)wr * 192;
    op[lane]       = __float2bfloat16((v0 - mu) * rs * g[lane]       + bb[lane]);
    op[lane + 64]  = __float2bfloat16((v1 - mu) * rs * g[lane + 64]  + bb[lane + 64]);
    op[lane + 128] = __float2bfloat16((v2 - mu) * rs * g[lane + 128] + bb[lane + 128]);
}

// ---------------- MFMA attention: one wave per (window, head); token-order gather/scatter ----------------
__global__ __launch_bounds__(64)
void attn_mfma(const __hip_bfloat16* __restrict__ qkv, const float* __restrict__ rpb,
               __hip_bfloat16* __restrict__ out, int shift)
{
    __shared__ float rp_s[169];
    __shared__ __align__(16) unsigned short Ps[64 * 72];   // P[n][m] bf16, stride 72
    const int win = blockIdx.x, head = blockIdx.y;
    const int lane = threadIdx.x;
    const int q = lane >> 4, l = lane & 15;
    const int bl = win >> 6, wrem = win & 63;
    const int wh = wrem >> 3, ww = wrem & 7;
    const __hip_bfloat16* base = qkv + head * 32;

    for (int i = lane; i < 169; i += 64) rp_s[i] = rpb[i * 6 + head];

    auto tokof = [&](int m) -> int {
        int mi = (m * 37) >> 8; int mj = m - mi * 7;
        int hh = wh * 7 + mi + shift; if (hh >= 56) hh -= 56;
        int wp = ww * 7 + mj + shift; if (wp >= 56) wp -= 56;
        return bl * 3136 + hh * 56 + wp;
    };

    // K A-frags (A[m=l][k=q*8+j]) and Q B-frags (B[k=q*8+j][n=l]), row-clamped
    short8 kf[4], qf[4];
    #pragma unroll
    for (int t = 0; t < 4; ++t) {
        int m = t * 16 + l; int mc = m < 49 ? m : 48;
        int r = tokof(mc);
        kf[t] = *(const short8*)(base + (size_t)r * 576 + 192 + q * 8);
        qf[t] = *(const short8*)(base + (size_t)r * 576 + q * 8);
    }
    floatx4 st[4][4];
    #pragma unroll
    for (int mt = 0; mt < 4; ++mt)
        #pragma unroll
        for (int nt = 0; nt < 4; ++nt) {
            floatx4 z = {0.f, 0.f, 0.f, 0.f};
            st[mt][nt] = __builtin_amdgcn_mfma_f32_16x16x32_bf16(kf[mt], qf[nt], z, 0, 0, 0);
        }

    // V B-frags (B[k=m][j=d]): u16 gather, row-clamped
    short8 vb[2][2];
    #pragma unroll
    for (int mk = 0; mk < 2; ++mk)
        #pragma unroll
        for (int j = 0; j < 8; ++j) {
            int m = mk * 32 + q * 8 + j; int mc = m < 49 ? m : 48;
            int r = tokof(mc);
            const short* vp = (const short*)(base + (size_t)r * 576 + 384 + l);
            vb[mk][0][j] = vp[0];
            vb[mk][1][j] = vp[16];
        }

    const bool edgeH = (wh == 7), edgeW = (ww == 7);
    int mi[16], mj[16], idm[16]; bool mok[16];
    #pragma unroll
    for (int mt = 0; mt < 4; ++mt)
        #pragma unroll
        for (int r = 0; r < 4; ++r) {
            int ii = mt * 4 + r;
            int m = mt * 16 + q * 4 + r;
            int d7 = (m * 37) >> 8;
            mi[ii] = d7; mj[ii] = m - d7 * 7;
            mok[ii] = (m < 49);
            int ih = edgeH ? (d7 < 4 ? 1 : 2) : 0;
            int iw = edgeW ? ((m - d7 * 7) < 4 ? 1 : 2) : 0;
            idm[ii] = ih * 3 + iw;
        }
    __syncthreads();

    #pragma unroll
    for (int nt = 0; nt < 4; ++nt) {
        int n = nt * 16 + l;
        int ri = (n * 37) >> 8; int rj = n - ri * 7;
        int ihn = edgeH ? (ri < 4 ? 1 : 2) : 0;
        int iwn = edgeW ? (rj < 4 ? 1 : 2) : 0;
        int idn = ihn * 3 + iwn;
        float sv[16];
        float mx = -3e38f;
        #pragma unroll
        for (int mt = 0; mt < 4; ++mt)
            #pragma unroll
            for (int r = 0; r < 4; ++r) {
                int ii = mt * 4 + r;
                float s = st[mt][nt][r] * SCALE_F + rp_s[(ri - mi[ii] + 6) * 13 + (rj - mj[ii] + 6)];
                if (shift > 0 && idm[ii] != idn) s -= 100.f;
                if (!mok[ii]) s = -3e38f;
                sv[ii] = s;
                mx = fmaxf(mx, s);
            }
        mx = fmaxf(mx, __shfl_xor(mx, 16));
        mx = fmaxf(mx, __shfl_xor(mx, 32));
        float sum = 0.f;
        #pragma unroll
        for (int ii = 0; ii < 16; ++ii) { float e = __expf(sv[ii] - mx); sv[ii] = e; sum += e; }
        sum += __shfl_xor(sum, 16);
        sum += __shfl_xor(sum, 32);
        float inv = 1.f / sum;
        #pragma unroll
        for (int mt = 0; mt < 4; ++mt) {
            ushort4v pk;
            #pragma unroll
            for (int r = 0; r < 4; ++r) {
                __hip_bfloat16 h = __float2bfloat16(sv[mt * 4 + r] * inv);
                pk[r] = *(unsigned short*)&h;
            }
            *(ushort4v*)(&Ps[(size_t)(nt * 16 + l) * 72 + mt * 16 + q * 4]) = pk;
        }
    }
    __syncthreads();

    floatx4 o[4][2];
    #pragma unroll
    for (int nt = 0; nt < 4; ++nt)
        #pragma unroll
        for (int dt = 0; dt < 2; ++dt) o[nt][dt] = floatx4{0.f, 0.f, 0.f, 0.f};
    #pragma unroll
    for (int mk = 0; mk < 2; ++mk)
        #pragma unroll
        for (int nt = 0; nt < 4; ++nt) {
            short8 pf = *(const short8*)(&Ps[(size_t)(nt * 16 + l) * 72 + mk * 32 + q * 8]);
            #pragma unroll
            for (int dt = 0; dt < 2; ++dt)
                o[nt][dt] = __builtin_amdgcn_mfma_f32_16x16x32_bf16(pf, vb[mk][dt], o[nt][dt], 0, 0, 0);
        }
    #pragma unroll
    for (int nt = 0; nt < 4; ++nt)
        #pragma unroll
        for (int r = 0; r < 4; ++r) {
            int n = nt * 16 + q * 4 + r;
            if (n < 49) {
                int tn = tokof(n);
                __hip_bfloat16* op = out + (size_t)tn * 192 + head * 32 + l;
                op[0]  = __float2bfloat16(o[nt][0][r]);
                op[16] = __float2bfloat16(o[nt][1][r]);
            }
        }
}

// ======== shared GEMM pieces: A-tile (128 x 192) LDS-resident, padded stride 200 ========
#define AST 200

__device__ __forceinline__ void stage_a192(const __hip_bfloat16* Atile, __hip_bfloat16* As, int tid)
{
    #pragma unroll
    for (int i = 0; i < 12; ++i) {
        int c = i * 256 + tid;
        int row = (c * 2731) >> 16;   // c / 24
        int col = c - row * 24;
        uint4 v = *(const uint4*)(Atile + (size_t)c * 8);
        *(uint4*)(As + row * AST + col * 8) = v;
    }
}

__device__ __forceinline__ void stage_b192(const __hip_bfloat16* Btile, __hip_bfloat16* Bs, int tid)
{
    #pragma unroll
    for (int i = 0; i < 6; ++i) {
        int c = i * 256 + tid;
        int row = (c * 2731) >> 16;
        int col = c - row * 24;
        uint4 v = *(const uint4*)(Btile + (size_t)c * 8);
        *(uint4*)(Bs + row * AST + col * 8) = v;
    }
}

// ---- async B-tile stage: 64x192 bf16 (24576B) via global_load_lds width=16,
// linear LDS dest + inverse-swizzled per-lane SOURCE (swizzle: byte ^= (row&7)<<4).
__device__ __forceinline__ void stage_b_async(const __hip_bfloat16* __restrict__ Wtile,
                                              void* BsBuf, const int* srcoff, int wave)
{
    const char* src = (const char*)Wtile;
    char* dst = (char*)BsBuf + wave * 6144;
    #pragma unroll
    for (int j = 0; j < 6; ++j) {
        __builtin_amdgcn_global_load_lds(
            (const __attribute__((address_space(1))) void*)(src + srcoff[j]),
            (__attribute__((address_space(3))) void*)(dst + j * 1024),
            16, 0, 0);
    }
}

// ---- async A-tile stage: 128x192 bf16 (49152B), same swizzle, into smem[0..49152)
__device__ __forceinline__ void stage_a_async(const __hip_bfloat16* __restrict__ Atile,
                                              void* smem, const int* asrc, int wave)
{
    const char* src = (const char*)Atile;
    char* dst = (char*)smem + wave * 1024;
    #pragma unroll
    for (int i = 0; i < 12; ++i) {
        __builtin_amdgcn_global_load_lds(
            (const __attribute__((address_space(1))) void*)(src + asrc[i]),
            (__attribute__((address_space(3))) void*)(dst + i * 4096),
            16, 0, 0);
    }
}

// ---------------- gemm_k192<EPI,NT>: K=192, all NT col-tiles in-block ----------------
// A staged through LDS once (XOR-swizzled), read into registers (af[4][6]); the SAME
// LDS array is then reused as the B double-buffer -> af ds_reads alias later LDS
// writes so the compiler cannot rematerialize them (they stay in VGPRs).
// One __syncthreads per ct: issue stage(ct+1) -> compute ct -> sync -> stores(ct).
// Stores drain at the NEXT sync, a full compute phase later (never on critical path).
// Wave tile 64x32 (2x2 wave grid): 12 swizzled ds_read_b128 feed 48 MFMA per ct.
// EPI 0: bias, bf16 store; EPI 1: bias + GELU, bf16 store
template<int EPI, int NT>
__global__ __launch_bounds__(256, 2)
void gemm_k192(const __hip_bfloat16* __restrict__ A,
               const __hip_bfloat16* __restrict__ Wt,
               const float* __restrict__ bias,
               __hip_bfloat16* __restrict__ out, int ld)
{
    // 49152 B: phase 1 = A tile (128 x 384B rows); phase 2 = B dbuf (2 x 64 x 384B)
    __shared__ __align__(16) unsigned short smem[128 * 192];
    const int tid = threadIdx.x;
    const int wave = tid >> 6, lane = tid & 63;
    const int q = lane >> 4, l = lane & 15;
    const int wr = wave >> 1, wc = wave & 1;
    const int row0 = blockIdx.x * 128;

    // ---- per-lane swizzled SOURCE offsets for A staging (granule g = i*256 + tid)
    int asrc[12];
    #pragma unroll
    for (int i = 0; i < 12; ++i) {
        int g = i * 256 + tid;
        int row = (g * 2731) >> 16;          // g / 24
        int col = g - row * 24;
        asrc[i] = row * 384 + ((col ^ (row & 7)) << 4);
    }
    stage_a_async(A + (size_t)row0 * 192, smem, asrc, wave);

    // ---- per-lane swizzled SOURCE offsets for B staging (granule g = (wave*6+j)*64+lane)
    int srcoff[6];
    #pragma unroll
    for (int j = 0; j < 6; ++j) {
        int g = (wave * 6 + j) * 64 + lane;
        int row = (g * 2731) >> 16;
        int col = g - row * 24;
        srcoff[j] = row * 384 + ((col ^ (row & 7)) << 4);
    }

    // ---- swizzled fragment-read offsets within a 384B row: granule (k*4+q) ^ (l&7)
    int xk[6];
    #pragma unroll
    for (int k = 0; k < 6; ++k) xk[k] = ((k * 4 + q) ^ (l & 7)) << 4;

    __syncthreads();   // A tile staged (drains vmcnt)

    // ---- A fragments -> registers: rows wr*64 .. +63, conflict-free swizzled reads
    short8 af[4][6];
    const char* sbase = (const char*)smem;
    #pragma unroll
    for (int rt = 0; rt < 4; ++rt) {
        int rb = (wr * 64 + rt * 16 + l) * 384;
        #pragma unroll
        for (int k = 0; k < 6; ++k)
            af[rt][k] = *(const short8*)(sbase + rb + xk[k]);
    }

    __syncthreads();   // all waves done reading A region (drains lgkm before barrier)

    stage_b_async(Wt, smem, srcoff, wave);            // ct0 -> buf0 (bytes [0,24576))
    __syncthreads();   // buf0 ready (one-time serial drain)

    for (int ct = 0; ct < NT; ++ct) {
        if (ct + 1 < NT)
            stage_b_async(Wt + (size_t)(ct + 1) * 64 * 192,
                          (char*)smem + ((ct + 1) & 1) * 24576, srcoff, wave);

        const char* bsb = (const char*)smem + (ct & 1) * 24576;
        floatx4 acc[4][2];
        #pragma unroll
        for (int rt = 0; rt < 4; ++rt)
            #pragma unroll
            for (int c = 0; c < 2; ++c) acc[rt][c] = floatx4{0.f, 0.f, 0.f, 0.f};

        #pragma unroll
        for (int k = 0; k < 6; ++k) {
            #pragma unroll
            for (int c = 0; c < 2; ++c) {
                short8 bf = *(const short8*)(bsb + ((wc * 2 + c) * 16 + l) * 384 + xk[k]);
                #pragma unroll
                for (int rt = 0; rt < 4; ++rt)
                    acc[rt][c] = __builtin_amdgcn_mfma_f32_16x16x32_bf16(af[rt][k], bf, acc[rt][c], 0, 0, 0);
            }
        }

        __syncthreads();   // drains stage(ct+1) + stores(ct-1); all waves done with buf[ct&1]

        #pragma unroll
        for (int c = 0; c < 2; ++c) {
            int col = ct * 64 + wc * 32 + c * 16 + l;
            float bz = bias[col];
            #pragma unroll
            for (int rt = 0; rt < 4; ++rt)
                #pragma unroll
                for (int rr = 0; rr < 4; ++rr) {
                    int row = row0 + wr * 64 + rt * 16 + q * 4 + rr;
                    float v = acc[rt][c][rr] + bz;
                    if constexpr (EPI == 1)
                        v = 0.5f * v * (1.f + erff(v * 0.70710678118654752f));
                    out[(size_t)row * ld + col] = __float2bfloat16(v);
                }
        }
    }
}

// ---------------- proj GEMM (K=192, N=192) + residual + fused LN2 ----------------
__global__ __launch_bounds__(256)
void gemm_proj_ln(const __hip_bfloat16* __restrict__ A,
                  const __hip_bfloat16* __restrict__ Wt,
                  const float* __restrict__ pb,
                  const float* __restrict__ g2, const float* __restrict__ b2,
                  const float* __restrict__ resid, float* __restrict__ Rout,
                  __hip_bfloat16* __restrict__ lnout, int b0)
{
    __shared__ __align__(16) __hip_bfloat16 As[128 * AST];
    __shared__ __align__(16) __hip_bfloat16 Bs[64 * AST];
    const int tid = threadIdx.x;
    const int wave = tid >> 6, lane = tid & 63;
    const int q = lane >> 4, l = lane & 15;
    const int row0 = blockIdx.x * 128;

    stage_a192(A + (size_t)row0 * 192, As, tid);

    floatx4 acc[2][12];
    #pragma unroll
    for (int rt = 0; rt < 2; ++rt)
        #pragma unroll
        for (int j = 0; j < 12; ++j) acc[rt][j] = floatx4{0.f, 0.f, 0.f, 0.f};

    for (int ct = 0; ct < 3; ++ct) {
        __syncthreads();
        stage_b192(Wt + (size_t)ct * 64 * 192, Bs, tid);
        __syncthreads();
        #pragma unroll
        for (int k = 0; k < 6; ++k) {
            short8 a0 = *(const short8*)(As + (wave * 32 + l) * AST + k * 32 + q * 8);
            short8 a1 = *(const short8*)(As + (wave * 32 + 16 + l) * AST + k * 32 + q * 8);
            #pragma unroll
            for (int c = 0; c < 4; ++c) {
                short8 bf = *(const short8*)(Bs + (c * 16 + l) * AST + k * 32 + q * 8);
                acc[0][ct * 4 + c] = __builtin_amdgcn_mfma_f32_16x16x32_bf16(a0, bf, acc[0][ct * 4 + c], 0, 0, 0);
                acc[1][ct * 4 + c] = __builtin_amdgcn_mfma_f32_16x16x32_bf16(a1, bf, acc[1][ct * 4 + c], 0, 0, 0);
            }
        }
    }

    float gj[12], bj[12], pbj[12];
    #pragma unroll
    for (int j = 0; j < 12; ++j) {
        int col = (j >> 2) * 64 + (j & 3) * 16 + l;
        gj[j] = g2[col]; bj[j] = b2[col]; pbj[j] = pb[col];
    }
    #pragma unroll
    for (int rt = 0; rt < 2; ++rt)
        #pragma unroll
        for (int rr = 0; rr < 4; ++rr) {
            int row = row0 + wave * 32 + rt * 16 + q * 4 + rr;
            size_t rb = ((size_t)b0 * 3136 + row) * 192;
            float y[12];
            float s = 0.f, ss = 0.f;
            #pragma unroll
            for (int j = 0; j < 12; ++j) {
                int col = (j >> 2) * 64 + (j & 3) * 16 + l;
                float v = acc[rt][j][rr] + pbj[j] + resid[rb + col];
                y[j] = v; s += v; ss += v * v;
                Rout[rb + col] = v;
            }
            s += __shfl_xor(s, 1); ss += __shfl_xor(ss, 1);
            s += __shfl_xor(s, 2); ss += __shfl_xor(ss, 2);
            s += __shfl_xor(s, 4); ss += __shfl_xor(ss, 4);
            s += __shfl_xor(s, 8); ss += __shfl_xor(ss, 8);
            float mu = s * (1.f / 192.f);
            float rs = rsqrtf(ss * (1.f / 192.f) - mu * mu + 1e-5f);
            #pragma unroll
            for (int j = 0; j < 12; ++j) {
                int col = (j >> 2) * 64 + (j & 3) * 16 + l;
                lnout[(size_t)row * 192 + col] = __float2bfloat16((y[j] - mu) * rs * gj[j] + bj[j]);
            }
        }
}

// ---------------- fc2 GEMM (K=768, N=192) + residual -> fp32 out ----------------
// Latency-bound fix (round 4): counted vmcnt + raw barriers. 3 LDS buffers,
// stage depth 2 (body t issues stage(t+2)); per-body vmem = 3 stage + 2 af,
// order pinned by memory clobbers -> ops-after-stage(t) = exactly 7, so
// s_waitcnt vmcnt(7) guarantees stage(t) landed while keeping stage(t+1),
// stage(t+2) and af prefetches in flight across the barrier. No stores in
// the loop (the round-1 vmcnt poison), so the count is exact.
// K-major granule layout (ko*1024 + n*16): lane-consecutive 16B reads,
// conflict-free (verified: SQ_LDS_BANK_CONFLICT = 0). 36.8KB LDS, (256,4)
// -> 4 blocks/CU.
__device__ __forceinline__ void fc2_stage_b(const __hip_bfloat16* __restrict__ Wt,
                                            void* bufbase, int ct, int kc,
                                            int wave, int lane)
{
    // tile (ct,kc): Wt rows n = ct*64+lane (row = 1536 B), K-bytes kc*192 + ko*16
    // LDS granule (ko,n) -> ko*1024 + n*16 ; ko = wave*3 + j
    const char* src = (const char*)Wt + (size_t)(ct * 64 + lane) * 1536 + kc * 192 + wave * 48;
    char* dst = (char*)bufbase + wave * 3072;
    #pragma unroll
    for (int j = 0; j < 3; ++j) {
        __builtin_amdgcn_global_load_lds(
            (const __attribute__((address_space(1))) void*)(src + j * 16),
            (__attribute__((address_space(3))) void*)(dst + j * 1024),
            16, 0, 0);
    }
}

__global__ __launch_bounds__(256, 4)
void gemm_fc2(const __hip_bfloat16* __restrict__ A,
              const __hip_bfloat16* __restrict__ Wt,
              const float* __restrict__ bias,
              const float* __restrict__ resid, float* __restrict__ out, int b0)
{
    __shared__ __align__(16) char Bs[3][12288];
    const int tid = threadIdx.x;
    const int wave = tid >> 6, lane = tid & 63;
    const int q = lane >> 4, l = lane & 15;
    const int wr = wave >> 1, wc = wave & 1;
    const int row0 = blockIdx.x * 64;

    // per-lane A base (bytes): row = row0 + wr*32 + l (rt=0) / +16 (rt=1); +q*16 B
    const char* a0 = (const char*)A + ((size_t)(row0 + wr * 32 + l) * 768 + q * 8) * 2;
    const char* a1 = a0 + 16 * 1536;

    // ---- prologue: pinned order stage(0), stage(1), af0 (clobbers pin FIFO order)
    fc2_stage_b(Wt, Bs[0], 0, 0, wave, lane);
    asm volatile("" ::: "memory");
    fc2_stage_b(Wt, Bs[1], 1, 0, wave, lane);
    asm volatile("" ::: "memory");

    // af[buf][rt][k]: A[row][kc*96 + k*32 + q*8 .. +8] -> byte off kc*192 + k*64
    short8 af[2][2][3];
    #pragma unroll
    for (int k = 0; k < 3; ++k) {
        af[0][0][k] = *(const short8*)(a0 + k * 64);
        af[0][1][k] = *(const short8*)(a1 + k * 64);
    }

    floatx4 acc[3][2][2];
    #pragma unroll
    for (int ct = 0; ct < 3; ++ct)
        #pragma unroll
        for (int rt = 0; rt < 2; ++rt)
            #pragma unroll
            for (int c = 0; c < 2; ++c) acc[ct][rt][c] = floatx4{0.f, 0.f, 0.f, 0.f};

    #pragma unroll
    for (int kc = 0; kc < 8; ++kc) {
        const int cur = kc & 1, nxt = cur ^ 1;
        #pragma unroll
        for (int ct = 0; ct < 3; ++ct) {
            const int t = kc * 3 + ct;
            // stage(t) landed; stage(t+1/t+2) + af prefetches stay in flight
            asm volatile("s_waitcnt vmcnt(7)" ::: "memory");
            __builtin_amdgcn_s_barrier();
            asm volatile("" ::: "memory");

            {   // stage t+2 (tail wraps to tiles 0/1: dummy re-stage into dead
                // buffers, keeps per-body vmem op count uniform at 3+2)
                const int ts = (t + 2) % 24;
                fc2_stage_b(Wt, Bs[(t + 2) % 3], ts % 3, ts / 3, wave, lane);
            }
            asm volatile("" ::: "memory");
            {   // af prefetch: 2 loads/body, kc clamped at tail (dead reload)
                const int kcn = (kc < 7) ? kc + 1 : 7;
                af[nxt][0][ct] = *(const short8*)(a0 + kcn * 192 + ct * 64);
                af[nxt][1][ct] = *(const short8*)(a1 + kcn * 192 + ct * 64);
            }

            const char* bsb = Bs[t % 3];
            #pragma unroll
            for (int k = 0; k < 3; ++k) {
                #pragma unroll
                for (int c = 0; c < 2; ++c) {
                    short8 bf = *(const short8*)(bsb + k * 4096 + q * 1024
                                                 + (wc * 32 + c * 16 + l) * 16);
                    #pragma unroll
                    for (int rt = 0; rt < 2; ++rt)
                        acc[ct][rt][c] = __builtin_amdgcn_mfma_f32_16x16x32_bf16(
                            af[cur][rt][k], bf, acc[ct][rt][c], 0, 0, 0);
                }
            }
        }
    }

    // ---- epilogue: bias + residual -> fp32 out
    #pragma unroll
    for (int ct = 0; ct < 3; ++ct)
        #pragma unroll
        for (int c = 0; c < 2; ++c) {
            int col = ct * 64 + wc * 32 + c * 16 + l;
            float bz = bias[col];
            #pragma unroll
            for (int rt = 0; rt < 2; ++rt)
                #pragma unroll
                for (int rr = 0; rr < 4; ++rr) {
                    int row = row0 + wr * 32 + rt * 16 + q * 4 + rr;
                    size_t rb = ((size_t)b0 * 3136 + row) * 192;
                    out[rb + col] = resid[rb + col] + acc[ct][rt][c][rr] + bz;
                }
        }
}

extern "C" void kernel_launch(void* const* d_in, const int* in_sizes, int n_in,
                              void* d_out, int out_size, void* d_ws, size_t ws_size,
                              hipStream_t stream)
{
    const float* x      = (const float*)d_in[0];
    const float* ln1_g  = (const float*)d_in[1];
    const float* ln1_b  = (const float*)d_in[2];
    const float* qkv_w  = (const float*)d_in[3];
    const float* qkv_b  = (const float*)d_in[4];
    const float* rpb    = (const float*)d_in[5];
    const float* proj_w = (const float*)d_in[6];
    const float* proj_b = (const float*)d_in[7];
    const float* ln2_g  = (const float*)d_in[8];
    const float* ln2_b  = (const float*)d_in[9];
    const float* fc1_w  = (const float*)d_in[10];
    const float* fc1_b  = (const float*)d_in[11];
    const float* fc2_w  = (const float*)d_in[12];
    const float* fc2_b  = (const float*)d_in[13];

    char* ws = (char*)d_ws;
    const size_t RN = 200704ull;

    int CB = 64;
    auto need = [&](int cb) -> size_t {
        return RN * 192 * 4                               // fp32 residual stream
             + (size_t)cb * 3136 * (192 + 768 + 192) * 2  // bufA + bufB + bufC (bf16)
             + 884736ull * 2 + 4096;
    };
    while (CB > 2 && need(CB) > ws_size) CB >>= 1;   // CB even => M % 128 == 0

    float* R = (float*)ws;
    size_t off = RN * 192 * 4;
    __hip_bfloat16* bufA = (__hip_bfloat16*)(ws + off); off += (size_t)CB * 3136 * 192 * 2;
    __hip_bfloat16* bufB = (__hip_bfloat16*)(ws + off); off += (size_t)CB * 3136 * 768 * 2;
    __hip_bfloat16* bufC = (__hip_bfloat16*)(ws + off); off += (size_t)CB * 3136 * 192 * 2;
    __hip_bfloat16* wreg = (__hip_bfloat16*)(ws + off);

    __hip_bfloat16 *qkvWt[2], *projWt[2], *fc1Wt[2], *fc2Wt[2];
    size_t woff = 0;
    for (int d = 0; d < 2; ++d) { qkvWt[d] = wreg + woff; woff += 576 * 192; }
    for (int d = 0; d < 2; ++d) { projWt[d] = wreg + woff; woff += 192 * 192; }
    for (int d = 0; d < 2; ++d) { fc1Wt[d] = wreg + woff; woff += 768 * 192; }
    for (int d = 0; d < 2; ++d) { fc2Wt[d] = wreg + woff; woff += 192 * 768; }

    for (int d = 0; d < 2; ++d) {
        wcast_t<<<(192 * 576 + 255) / 256, 256, 0, stream>>>(qkv_w + (size_t)d * 192 * 576, qkvWt[d], 192, 576);
        wcast_t<<<(192 * 192 + 255) / 256, 256, 0, stream>>>(proj_w + (size_t)d * 192 * 192, projWt[d], 192, 192);
        wcast_t<<<(192 * 768 + 255) / 256, 256, 0, stream>>>(fc1_w + (size_t)d * 192 * 768, fc1Wt[d], 192, 768);
        wcast_t<<<(768 * 192 + 255) / 256, 256, 0, stream>>>(fc2_w + (size_t)d * 768 * 192, fc2Wt[d], 768, 192);
    }

    const int nrows = CB * 3136;
    const int gm = nrows / 128;
    const int gm64 = nrows / 64;
    for (int d = 0; d < 2; ++d) {
        int shift = d ? 3 : 0;
        const float* residA = d ? R : x;
        const float* rpbd = rpb + (size_t)d * 169 * 6;
        float* outF = d ? (float*)d_out : R;

        for (int b0 = 0; b0 < 64; b0 += CB) {
            ln_kernel<<<nrows / 4, 256, 0, stream>>>(residA, ln1_g + d * 192, ln1_b + d * 192, bufA, b0);
            gemm_k192<0, 9><<<gm, 256, 0, stream>>>(bufA, qkvWt[d], qkv_b + d * 576, bufB, 576);
            attn_mfma<<<dim3(CB * 64, 6), 64, 0, stream>>>(bufB, rpbd, bufA, shift);
            gemm_proj_ln<<<gm, 256, 0, stream>>>(bufA, projWt[d], proj_b + d * 192,
                                                 ln2_g + d * 192, ln2_b + d * 192,
                                                 residA, R, bufC, b0);
            gemm_k192<1, 12><<<gm, 256, 0, stream>>>(bufC, fc1Wt[d], fc1_b + d * 768, bufB, 768);
            gemm_fc2<<<gm64, 256, 0, stream>>>(bufB, fc2Wt[d], fc2_b + d * 192, R, outF, b0);
        }
    }
}

// Round 5
// 1818.505 us; speedup vs baseline: 1.1502x; 1.1502x over previous
//
#include <hip/hip_runtime.h>
#include <hip/hip_bf16.h>
#include <math.h>

typedef __attribute__((ext_vector_type(8))) short short8;
typedef __attribute__((ext_vector_type(4))) float floatx4;
typedef __attribute__((ext_vector_type(4))) unsigned short ushort4v;

#define SCALE_F 0.17677669529663689f  // 1/sqrt(32)

__device__ __forceinline__ float bf2f(__hip_bfloat16 v){ return __bfloat162float(v); }

// ---------------- weight cast + transpose: src fp32 (K x N) -> dst bf16 (N x K) ----------------
__global__ void wcast_t(const float* __restrict__ src, __hip_bfloat16* __restrict__ dst, int K, int N)
{
    int idx = blockIdx.x * 256 + threadIdx.x;
    if (idx >= K * N) return;
    int n = idx / K, k = idx - n * K;
    dst[idx] = __float2bfloat16(src[(size_t)k * N + n]);
}

// ---------------- LayerNorm (token order) -> bf16 rows ----------------
__global__ __launch_bounds__(256)
void ln_kernel(const float* __restrict__ x, const float* __restrict__ g,
               const float* __restrict__ bb, __hip_bfloat16* __restrict__ out, int b0)
{
    int wave = threadIdx.x >> 6, lane = threadIdx.x & 63;
    int wr = blockIdx.x * 4 + wave;
    const float* xr = x + ((size_t)b0 * 3136 + wr) * 192;
    float v0 = xr[lane], v1 = xr[lane + 64], v2 = xr[lane + 128];
    float s = v0 + v1 + v2, ss = v0 * v0 + v1 * v1 + v2 * v2;
    #pragma unroll
    for (int o = 32; o; o >>= 1) { s += __shfl_xor(s, o); ss += __shfl_xor(ss, o); }
    float mu = s * (1.f / 192.f);
    float rs = rsqrtf(ss * (1.f / 192.f) - mu * mu + 1e-5f);
    __hip_bfloat16* op = out + (size_t)wr * 192;
    op[lane]       = __float2bfloat16((v0 - mu) * rs * g[lane]       + bb[lane]);
    op[lane + 64]  = __float2bfloat16((v1 - mu) * rs * g[lane + 64]  + bb[lane + 64]);
    op[lane + 128] = __float2bfloat16((v2 - mu) * rs * g[lane + 128] + bb[lane + 128]);
}

// ---------------- MFMA attention: one wave per (window, head); token-order gather/scatter ----------------
__global__ __launch_bounds__(64)
void attn_mfma(const __hip_bfloat16* __restrict__ qkv, const float* __restrict__ rpb,
               __hip_bfloat16* __restrict__ out, int shift)
{
    __shared__ float rp_s[169];
    __shared__ __align__(16) unsigned short Ps[64 * 72];   // P[n][m] bf16, stride 72
    const int win = blockIdx.x, head = blockIdx.y;
    const int lane = threadIdx.x;
    const int q = lane >> 4, l = lane & 15;
    const int bl = win >> 6, wrem = win & 63;
    const int wh = wrem >> 3, ww = wrem & 7;
    const __hip_bfloat16* base = qkv + head * 32;

    for (int i = lane; i < 169; i += 64) rp_s[i] = rpb[i * 6 + head];

    auto tokof = [&](int m) -> int {
        int mi = (m * 37) >> 8; int mj = m - mi * 7;
        int hh = wh * 7 + mi + shift; if (hh >= 56) hh -= 56;
        int wp = ww * 7 + mj + shift; if (wp >= 56) wp -= 56;
        return bl * 3136 + hh * 56 + wp;
    };

    // K A-frags (A[m=l][k=q*8+j]) and Q B-frags (B[k=q*8+j][n=l]), row-clamped
    short8 kf[4], qf[4];
    #pragma unroll
    for (int t = 0; t < 4; ++t) {
        int m = t * 16 + l; int mc = m < 49 ? m : 48;
        int r = tokof(mc);
        kf[t] = *(const short8*)(base + (size_t)r * 576 + 192 + q * 8);
        qf[t] = *(const short8*)(base + (size_t)r * 576 + q * 8);
    }
    floatx4 st[4][4];
    #pragma unroll
    for (int mt = 0; mt < 4; ++mt)
        #pragma unroll
        for (int nt = 0; nt < 4; ++nt) {
            floatx4 z = {0.f, 0.f, 0.f, 0.f};
            st[mt][nt] = __builtin_amdgcn_mfma_f32_16x16x32_bf16(kf[mt], qf[nt], z, 0, 0, 0);
        }

    // V B-frags (B[k=m][j=d]): u16 gather, row-clamped
    short8 vb[2][2];
    #pragma unroll
    for (int mk = 0; mk < 2; ++mk)
        #pragma unroll
        for (int j = 0; j < 8; ++j) {
            int m = mk * 32 + q * 8 + j; int mc = m < 49 ? m : 48;
            int r = tokof(mc);
            const short* vp = (const short*)(base + (size_t)r * 576 + 384 + l);
            vb[mk][0][j] = vp[0];
            vb[mk][1][j] = vp[16];
        }

    const bool edgeH = (wh == 7), edgeW = (ww == 7);
    int mi[16], mj[16], idm[16]; bool mok[16];
    #pragma unroll
    for (int mt = 0; mt < 4; ++mt)
        #pragma unroll
        for (int r = 0; r < 4; ++r) {
            int ii = mt * 4 + r;
            int m = mt * 16 + q * 4 + r;
            int d7 = (m * 37) >> 8;
            mi[ii] = d7; mj[ii] = m - d7 * 7;
            mok[ii] = (m < 49);
            int ih = edgeH ? (d7 < 4 ? 1 : 2) : 0;
            int iw = edgeW ? ((m - d7 * 7) < 4 ? 1 : 2) : 0;
            idm[ii] = ih * 3 + iw;
        }
    __syncthreads();

    #pragma unroll
    for (int nt = 0; nt < 4; ++nt) {
        int n = nt * 16 + l;
        int ri = (n * 37) >> 8; int rj = n - ri * 7;
        int ihn = edgeH ? (ri < 4 ? 1 : 2) : 0;
        int iwn = edgeW ? (rj < 4 ? 1 : 2) : 0;
        int idn = ihn * 3 + iwn;
        float sv[16];
        float mx = -3e38f;
        #pragma unroll
        for (int mt = 0; mt < 4; ++mt)
            #pragma unroll
            for (int r = 0; r < 4; ++r) {
                int ii = mt * 4 + r;
                float s = st[mt][nt][r] * SCALE_F + rp_s[(ri - mi[ii] + 6) * 13 + (rj - mj[ii] + 6)];
                if (shift > 0 && idm[ii] != idn) s -= 100.f;
                if (!mok[ii]) s = -3e38f;
                sv[ii] = s;
                mx = fmaxf(mx, s);
            }
        mx = fmaxf(mx, __shfl_xor(mx, 16));
        mx = fmaxf(mx, __shfl_xor(mx, 32));
        float sum = 0.f;
        #pragma unroll
        for (int ii = 0; ii < 16; ++ii) { float e = __expf(sv[ii] - mx); sv[ii] = e; sum += e; }
        sum += __shfl_xor(sum, 16);
        sum += __shfl_xor(sum, 32);
        float inv = 1.f / sum;
        #pragma unroll
        for (int mt = 0; mt < 4; ++mt) {
            ushort4v pk;
            #pragma unroll
            for (int r = 0; r < 4; ++r) {
                __hip_bfloat16 h = __float2bfloat16(sv[mt * 4 + r] * inv);
                pk[r] = *(unsigned short*)&h;
            }
            *(ushort4v*)(&Ps[(size_t)(nt * 16 + l) * 72 + mt * 16 + q * 4]) = pk;
        }
    }
    __syncthreads();

    floatx4 o[4][2];
    #pragma unroll
    for (int nt = 0; nt < 4; ++nt)
        #pragma unroll
        for (int dt = 0; dt < 2; ++dt) o[nt][dt] = floatx4{0.f, 0.f, 0.f, 0.f};
    #pragma unroll
    for (int mk = 0; mk < 2; ++mk)
        #pragma unroll
        for (int nt = 0; nt < 4; ++nt) {
            short8 pf = *(const short8*)(&Ps[(size_t)(nt * 16 + l) * 72 + mk * 32 + q * 8]);
            #pragma unroll
            for (int dt = 0; dt < 2; ++dt)
                o[nt][dt] = __builtin_amdgcn_mfma_f32_16x16x32_bf16(pf, vb[mk][dt], o[nt][dt], 0, 0, 0);
        }
    #pragma unroll
    for (int nt = 0; nt < 4; ++nt)
        #pragma unroll
        for (int r = 0; r < 4; ++r) {
            int n = nt * 16 + q * 4 + r;
            if (n < 49) {
                int tn = tokof(n);
                __hip_bfloat16* op = out + (size_t)tn * 192 + head * 32 + l;
                op[0]  = __float2bfloat16(o[nt][0][r]);
                op[16] = __float2bfloat16(o[nt][1][r]);
            }
        }
}

// ======== shared GEMM pieces ========
#define AST 200

__device__ __forceinline__ void stage_a192(const __hip_bfloat16* Atile, __hip_bfloat16* As, int tid)
{
    #pragma unroll
    for (int i = 0; i < 12; ++i) {
        int c = i * 256 + tid;
        int row = (c * 2731) >> 16;   // c / 24
        int col = c - row * 24;
        uint4 v = *(const uint4*)(Atile + (size_t)c * 8);
        *(uint4*)(As + row * AST + col * 8) = v;
    }
}

__device__ __forceinline__ void stage_b192(const __hip_bfloat16* Btile, __hip_bfloat16* Bs, int tid)
{
    #pragma unroll
    for (int i = 0; i < 6; ++i) {
        int c = i * 256 + tid;
        int row = (c * 2731) >> 16;
        int col = c - row * 24;
        uint4 v = *(const uint4*)(Btile + (size_t)c * 8);
        *(uint4*)(Bs + row * AST + col * 8) = v;
    }
}

// ---- async B-tile stage: 64x192 bf16 (24576B) via global_load_lds width=16,
// linear LDS dest + inverse-swizzled per-lane SOURCE (swizzle: byte ^= (row&7)<<4).
__device__ __forceinline__ void stage_b_async(const __hip_bfloat16* __restrict__ Wtile,
                                              void* BsBuf, const int* srcoff, int wave)
{
    const char* src = (const char*)Wtile;
    char* dst = (char*)BsBuf + wave * 6144;
    #pragma unroll
    for (int j = 0; j < 6; ++j) {
        __builtin_amdgcn_global_load_lds(
            (const __attribute__((address_space(1))) void*)(src + srcoff[j]),
            (__attribute__((address_space(3))) void*)(dst + j * 1024),
            16, 0, 0);
    }
}

// ---- async A-tile stage: 128x192 bf16 (49152B), same swizzle, into smem[0..49152)
__device__ __forceinline__ void stage_a_async(const __hip_bfloat16* __restrict__ Atile,
                                              void* smem, const int* asrc, int wave)
{
    const char* src = (const char*)Atile;
    char* dst = (char*)smem + wave * 1024;
    #pragma unroll
    for (int i = 0; i < 12; ++i) {
        __builtin_amdgcn_global_load_lds(
            (const __attribute__((address_space(1))) void*)(src + asrc[i]),
            (__attribute__((address_space(3))) void*)(dst + i * 4096),
            16, 0, 0);
    }
}

// ---------------- gemm_k192<EPI,NT>: K=192, all NT col-tiles in-block ----------------
// (proven round-2 structure; unchanged)
template<int EPI, int NT>
__global__ __launch_bounds__(256, 2)
void gemm_k192(const __hip_bfloat16* __restrict__ A,
               const __hip_bfloat16* __restrict__ Wt,
               const float* __restrict__ bias,
               __hip_bfloat16* __restrict__ out, int ld)
{
    // 49152 B: phase 1 = A tile (128 x 384B rows); phase 2 = B dbuf (2 x 64 x 384B)
    __shared__ __align__(16) unsigned short smem[128 * 192];
    const int tid = threadIdx.x;
    const int wave = tid >> 6, lane = tid & 63;
    const int q = lane >> 4, l = lane & 15;
    const int wr = wave >> 1, wc = wave & 1;
    const int row0 = blockIdx.x * 128;

    int asrc[12];
    #pragma unroll
    for (int i = 0; i < 12; ++i) {
        int g = i * 256 + tid;
        int row = (g * 2731) >> 16;          // g / 24
        int col = g - row * 24;
        asrc[i] = row * 384 + ((col ^ (row & 7)) << 4);
    }
    stage_a_async(A + (size_t)row0 * 192, smem, asrc, wave);

    int srcoff[6];
    #pragma unroll
    for (int j = 0; j < 6; ++j) {
        int g = (wave * 6 + j) * 64 + lane;
        int row = (g * 2731) >> 16;
        int col = g - row * 24;
        srcoff[j] = row * 384 + ((col ^ (row & 7)) << 4);
    }

    int xk[6];
    #pragma unroll
    for (int k = 0; k < 6; ++k) xk[k] = ((k * 4 + q) ^ (l & 7)) << 4;

    __syncthreads();   // A tile staged

    short8 af[4][6];
    const char* sbase = (const char*)smem;
    #pragma unroll
    for (int rt = 0; rt < 4; ++rt) {
        int rb = (wr * 64 + rt * 16 + l) * 384;
        #pragma unroll
        for (int k = 0; k < 6; ++k)
            af[rt][k] = *(const short8*)(sbase + rb + xk[k]);
    }

    __syncthreads();   // all waves done reading A region

    stage_b_async(Wt, smem, srcoff, wave);            // ct0 -> buf0
    __syncthreads();

    for (int ct = 0; ct < NT; ++ct) {
        if (ct + 1 < NT)
            stage_b_async(Wt + (size_t)(ct + 1) * 64 * 192,
                          (char*)smem + ((ct + 1) & 1) * 24576, srcoff, wave);

        const char* bsb = (const char*)smem + (ct & 1) * 24576;
        floatx4 acc[4][2];
        #pragma unroll
        for (int rt = 0; rt < 4; ++rt)
            #pragma unroll
            for (int c = 0; c < 2; ++c) acc[rt][c] = floatx4{0.f, 0.f, 0.f, 0.f};

        #pragma unroll
        for (int k = 0; k < 6; ++k) {
            #pragma unroll
            for (int c = 0; c < 2; ++c) {
                short8 bf = *(const short8*)(bsb + ((wc * 2 + c) * 16 + l) * 384 + xk[k]);
                #pragma unroll
                for (int rt = 0; rt < 4; ++rt)
                    acc[rt][c] = __builtin_amdgcn_mfma_f32_16x16x32_bf16(af[rt][k], bf, acc[rt][c], 0, 0, 0);
            }
        }

        __syncthreads();

        #pragma unroll
        for (int c = 0; c < 2; ++c) {
            int col = ct * 64 + wc * 32 + c * 16 + l;
            float bz = bias[col];
            #pragma unroll
            for (int rt = 0; rt < 4; ++rt)
                #pragma unroll
                for (int rr = 0; rr < 4; ++rr) {
                    int row = row0 + wr * 64 + rt * 16 + q * 4 + rr;
                    float v = acc[rt][c][rr] + bz;
                    if constexpr (EPI == 1)
                        v = 0.5f * v * (1.f + erff(v * 0.70710678118654752f));
                    out[(size_t)row * ld + col] = __float2bfloat16(v);
                }
        }
    }
}

// ---------------- proj GEMM (K=192, N=192) + residual + fused LN2 ----------------
// Ported to the proven k192 structure (round 5): A alias-staged through LDS into
// registers (af[2][6], wave owns rows wave*32..+31 x all 192 cols so the LN
// shuffle-epilogue is unchanged), async swizzled B double-buffer, one
// __syncthreads per ct, no stores in the loop. LDS 100KB -> 48KB.
__global__ __launch_bounds__(256, 2)
void gemm_proj_ln(const __hip_bfloat16* __restrict__ A,
                  const __hip_bfloat16* __restrict__ Wt,
                  const float* __restrict__ pb,
                  const float* __restrict__ g2, const float* __restrict__ b2,
                  const float* __restrict__ resid, float* __restrict__ Rout,
                  __hip_bfloat16* __restrict__ lnout, int b0)
{
    __shared__ __align__(16) unsigned short smem[128 * 192];
    const int tid = threadIdx.x;
    const int wave = tid >> 6, lane = tid & 63;
    const int q = lane >> 4, l = lane & 15;
    const int row0 = blockIdx.x * 128;

    int asrc[12];
    #pragma unroll
    for (int i = 0; i < 12; ++i) {
        int g = i * 256 + tid;
        int row = (g * 2731) >> 16;
        int col = g - row * 24;
        asrc[i] = row * 384 + ((col ^ (row & 7)) << 4);
    }
    stage_a_async(A + (size_t)row0 * 192, smem, asrc, wave);

    int srcoff[6];
    #pragma unroll
    for (int j = 0; j < 6; ++j) {
        int g = (wave * 6 + j) * 64 + lane;
        int row = (g * 2731) >> 16;
        int col = g - row * 24;
        srcoff[j] = row * 384 + ((col ^ (row & 7)) << 4);
    }
    int xk[6];
    #pragma unroll
    for (int k = 0; k < 6; ++k) xk[k] = ((k * 4 + q) ^ (l & 7)) << 4;

    __syncthreads();   // A tile staged

    // A fragments: wave owns rows wave*32 .. +31 (rt in {0,1})
    short8 af[2][6];
    const char* sbase = (const char*)smem;
    #pragma unroll
    for (int rt = 0; rt < 2; ++rt) {
        int rb = (wave * 32 + rt * 16 + l) * 384;
        #pragma unroll
        for (int k = 0; k < 6; ++k)
            af[rt][k] = *(const short8*)(sbase + rb + xk[k]);
    }

    __syncthreads();   // all waves done reading A region

    stage_b_async(Wt, smem, srcoff, wave);   // ct0 -> buf0
    __syncthreads();

    floatx4 acc[2][12];
    #pragma unroll
    for (int rt = 0; rt < 2; ++rt)
        #pragma unroll
        for (int j = 0; j < 12; ++j) acc[rt][j] = floatx4{0.f, 0.f, 0.f, 0.f};

    for (int ct = 0; ct < 3; ++ct) {
        if (ct + 1 < 3)
            stage_b_async(Wt + (size_t)(ct + 1) * 64 * 192,
                          (char*)smem + ((ct + 1) & 1) * 24576, srcoff, wave);

        const char* bsb = (const char*)smem + (ct & 1) * 24576;
        #pragma unroll
        for (int k = 0; k < 6; ++k) {
            #pragma unroll
            for (int c = 0; c < 4; ++c) {
                short8 bf = *(const short8*)(bsb + (c * 16 + l) * 384 + xk[k]);
                acc[0][ct * 4 + c] = __builtin_amdgcn_mfma_f32_16x16x32_bf16(af[0][k], bf, acc[0][ct * 4 + c], 0, 0, 0);
                acc[1][ct * 4 + c] = __builtin_amdgcn_mfma_f32_16x16x32_bf16(af[1][k], bf, acc[1][ct * 4 + c], 0, 0, 0);
            }
        }
        __syncthreads();
    }

    float gj[12], bj[12], pbj[12];
    #pragma unroll
    for (int j = 0; j < 12; ++j) {
        int col = (j >> 2) * 64 + (j & 3) * 16 + l;
        gj[j] = g2[col]; bj[j] = b2[col]; pbj[j] = pb[col];
    }
    #pragma unroll
    for (int rt = 0; rt < 2; ++rt)
        #pragma unroll
        for (int rr = 0; rr < 4; ++rr) {
            int row = row0 + wave * 32 + rt * 16 + q * 4 + rr;
            size_t rb = ((size_t)b0 * 3136 + row) * 192;
            float y[12];
            float s = 0.f, ss = 0.f;
            #pragma unroll
            for (int j = 0; j < 12; ++j) {
                int col = (j >> 2) * 64 + (j & 3) * 16 + l;
                float v = acc[rt][j][rr] + pbj[j] + resid[rb + col];
                y[j] = v; s += v; ss += v * v;
                Rout[rb + col] = v;
            }
            s += __shfl_xor(s, 1); ss += __shfl_xor(ss, 1);
            s += __shfl_xor(s, 2); ss += __shfl_xor(ss, 2);
            s += __shfl_xor(s, 4); ss += __shfl_xor(ss, 4);
            s += __shfl_xor(s, 8); ss += __shfl_xor(ss, 8);
            float mu = s * (1.f / 192.f);
            float rs = rsqrtf(ss * (1.f / 192.f) - mu * mu + 1e-5f);
            #pragma unroll
            for (int j = 0; j < 12; ++j) {
                int col = (j >> 2) * 64 + (j & 3) * 16 + l;
                lnout[(size_t)row * 192 + col] = __float2bfloat16((y[j] - mu) * rs * gj[j] + bj[j]);
            }
        }
}

// ---------------- fc2 GEMM (K=768, N=192) + residual -> fp32 out ----------------
// REVERTED to the round-2 version (proven 120.9 us). The 64-row counted-vmcnt
// restructures (rounds 3+4) both regressed: 3136 blocks re-read full Wt, only
// 12 MFMA/barrier, 3-deep staging chains -> more serialized latency exposures
// than this 128-row kernel (12 concurrent loads/thread per stage, 72 MFMA/kc).
__global__ __launch_bounds__(256)
void gemm_fc2(const __hip_bfloat16* __restrict__ A,
              const __hip_bfloat16* __restrict__ Wt,
              const float* __restrict__ bias,
              const float* __restrict__ resid, float* __restrict__ out, int b0)
{
    __shared__ __align__(16) __hip_bfloat16 As[128 * AST];
    __shared__ __align__(16) __hip_bfloat16 Bs[64 * AST];
    const int tid = threadIdx.x;
    const int wave = tid >> 6, lane = tid & 63;
    const int q = lane >> 4, l = lane & 15;
    const int row0 = blockIdx.x * 128;

    floatx4 acc[2][12];
    #pragma unroll
    for (int rt = 0; rt < 2; ++rt)
        #pragma unroll
        for (int j = 0; j < 12; ++j) acc[rt][j] = floatx4{0.f, 0.f, 0.f, 0.f};

    for (int kc = 0; kc < 4; ++kc) {
        __syncthreads();
        #pragma unroll
        for (int i = 0; i < 12; ++i) {
            int c = i * 256 + tid;
            int row = (c * 2731) >> 16;
            int col = c - row * 24;
            uint4 v = *(const uint4*)(A + (size_t)(row0 + row) * 768 + kc * 192 + col * 8);
            *(uint4*)(As + row * AST + col * 8) = v;
        }
        for (int ct = 0; ct < 3; ++ct) {
            __syncthreads();
            #pragma unroll
            for (int i = 0; i < 6; ++i) {
                int c = i * 256 + tid;
                int row = (c * 2731) >> 16;
                int col = c - row * 24;
                uint4 v = *(const uint4*)(Wt + (size_t)(ct * 64 + row) * 768 + kc * 192 + col * 8);
                *(uint4*)(Bs + row * AST + col * 8) = v;
            }
            __syncthreads();
            #pragma unroll
            for (int k = 0; k < 6; ++k) {
                short8 a0 = *(const short8*)(As + (wave * 32 + l) * AST + k * 32 + q * 8);
                short8 a1 = *(const short8*)(As + (wave * 32 + 16 + l) * AST + k * 32 + q * 8);
                #pragma unroll
                for (int c = 0; c < 4; ++c) {
                    short8 bf = *(const short8*)(Bs + (c * 16 + l) * AST + k * 32 + q * 8);
                    acc[0][ct * 4 + c] = __builtin_amdgcn_mfma_f32_16x16x32_bf16(a0, bf, acc[0][ct * 4 + c], 0, 0, 0);
                    acc[1][ct * 4 + c] = __builtin_amdgcn_mfma_f32_16x16x32_bf16(a1, bf, acc[1][ct * 4 + c], 0, 0, 0);
                }
            }
        }
    }

    float bzj[12];
    #pragma unroll
    for (int j = 0; j < 12; ++j) {
        int col = (j >> 2) * 64 + (j & 3) * 16 + l;
        bzj[j] = bias[col];
    }
    #pragma unroll
    for (int rt = 0; rt < 2; ++rt)
        #pragma unroll
        for (int rr = 0; rr < 4; ++rr) {
            int row = row0 + wave * 32 + rt * 16 + q * 4 + rr;
            size_t rb = ((size_t)b0 * 3136 + row) * 192;
            #pragma unroll
            for (int j = 0; j < 12; ++j) {
                int col = (j >> 2) * 64 + (j & 3) * 16 + l;
                out[rb + col] = resid[rb + col] + acc[rt][j][rr] + bzj[j];
            }
        }
}

extern "C" void kernel_launch(void* const* d_in, const int* in_sizes, int n_in,
                              void* d_out, int out_size, void* d_ws, size_t ws_size,
                              hipStream_t stream)
{
    const float* x      = (const float*)d_in[0];
    const float* ln1_g  = (const float*)d_in[1];
    const float* ln1_b  = (const float*)d_in[2];
    const float* qkv_w  = (const float*)d_in[3];
    const float* qkv_b  = (const float*)d_in[4];
    const float* rpb    = (const float*)d_in[5];
    const float* proj_w = (const float*)d_in[6];
    const float* proj_b = (const float*)d_in[7];
    const float* ln2_g  = (const float*)d_in[8];
    const float* ln2_b  = (const float*)d_in[9];
    const float* fc1_w  = (const float*)d_in[10];
    const float* fc1_b  = (const float*)d_in[11];
    const float* fc2_w  = (const float*)d_in[12];
    const float* fc2_b  = (const float*)d_in[13];

    char* ws = (char*)d_ws;
    const size_t RN = 200704ull;

    int CB = 64;
    auto need = [&](int cb) -> size_t {
        return RN * 192 * 4                               // fp32 residual stream
             + (size_t)cb * 3136 * (192 + 768 + 192) * 2  // bufA + bufB + bufC (bf16)
             + 884736ull * 2 + 4096;
    };
    while (CB > 2 && need(CB) > ws_size) CB >>= 1;   // CB even => M % 128 == 0

    float* R = (float*)ws;
    size_t off = RN * 192 * 4;
    __hip_bfloat16* bufA = (__hip_bfloat16*)(ws + off); off += (size_t)CB * 3136 * 192 * 2;
    __hip_bfloat16* bufB = (__hip_bfloat16*)(ws + off); off += (size_t)CB * 3136 * 768 * 2;
    __hip_bfloat16* bufC = (__hip_bfloat16*)(ws + off); off += (size_t)CB * 3136 * 192 * 2;
    __hip_bfloat16* wreg = (__hip_bfloat16*)(ws + off);

    __hip_bfloat16 *qkvWt[2], *projWt[2], *fc1Wt[2], *fc2Wt[2];
    size_t woff = 0;
    for (int d = 0; d < 2; ++d) { qkvWt[d] = wreg + woff; woff += 576 * 192; }
    for (int d = 0; d < 2; ++d) { projWt[d] = wreg + woff; woff += 192 * 192; }
    for (int d = 0; d < 2; ++d) { fc1Wt[d] = wreg + woff; woff += 768 * 192; }
    for (int d = 0; d < 2; ++d) { fc2Wt[d] = wreg + woff; woff += 192 * 768; }

    for (int d = 0; d < 2; ++d) {
        wcast_t<<<(192 * 576 + 255) / 256, 256, 0, stream>>>(qkv_w + (size_t)d * 192 * 576, qkvWt[d], 192, 576);
        wcast_t<<<(192 * 192 + 255) / 256, 256, 0, stream>>>(proj_w + (size_t)d * 192 * 192, projWt[d], 192, 192);
        wcast_t<<<(192 * 768 + 255) / 256, 256, 0, stream>>>(fc1_w + (size_t)d * 192 * 768, fc1Wt[d], 192, 768);
        wcast_t<<<(768 * 192 + 255) / 256, 256, 0, stream>>>(fc2_w + (size_t)d * 768 * 192, fc2Wt[d], 768, 192);
    }

    const int nrows = CB * 3136;
    const int gm = nrows / 128;
    for (int d = 0; d < 2; ++d) {
        int shift = d ? 3 : 0;
        const float* residA = d ? R : x;
        const float* rpbd = rpb + (size_t)d * 169 * 6;
        float* outF = d ? (float*)d_out : R;

        for (int b0 = 0; b0 < 64; b0 += CB) {
            ln_kernel<<<nrows / 4, 256, 0, stream>>>(residA, ln1_g + d * 192, ln1_b + d * 192, bufA, b0);
            gemm_k192<0, 9><<<gm, 256, 0, stream>>>(bufA, qkvWt[d], qkv_b + d * 576, bufB, 576);
            attn_mfma<<<dim3(CB * 64, 6), 64, 0, stream>>>(bufB, rpbd, bufA, shift);
            gemm_proj_ln<<<gm, 256, 0, stream>>>(bufA, projWt[d], proj_b + d * 192,
                                                 ln2_g + d * 192, ln2_b + d * 192,
                                                 residA, R, bufC, b0);
            gemm_k192<1, 12><<<gm, 256, 0, stream>>>(bufC, fc1Wt[d], fc1_b + d * 768, bufB, 768);
            gemm_fc2<<<gm, 256, 0, stream>>>(bufB, fc2Wt[d], fc2_b + d * 192, R, outF, b0);
        }
    }
}